// Round 8
// baseline (426.145 us; speedup 1.0000x reference)
//
#include <hip/hip_runtime.h>
#include <stdint.h>

#define NN 20000
#define MM 16000
#define DD 128
#define CT2 250       // 16000 / 64 col-tiles
#define SPLITS 32     // multiple of 8 -> split % 8 == XCD id (L2 locality)
#define RB 79         // ceil(20000/256) row blocks

typedef unsigned long long u64;
typedef _Float16 f16x8 __attribute__((ext_vector_type(8)));
typedef float f32x16 __attribute__((ext_vector_type(16)));

// One wave per rain row: y2[m] = ||rain[m]||^2 (fp32, unbiased — see r5/r6
// post-mortem: +512 bias coarsened accumulator ulp 8x and flipped argmins)
__global__ void k_y2(const float* __restrict__ rain, float* __restrict__ y2) {
    int row = blockIdx.x * 4 + (threadIdx.x >> 6);
    int lane = threadIdx.x & 63;
    if (row >= MM) return;
    float2 v = ((const float2*)(rain + (size_t)row * DD))[lane];
    float s = v.x * v.x + v.y * v.y;
    #pragma unroll
    for (int off = 32; off > 0; off >>= 1) s += __shfl_down(s, off);
    if (lane == 0) y2[row] = s;
}

// Split rain into fp16 hi/lo 64-col tile images (32KB per tile):
// tile tc: hi f16[0:8192], lo f16[8192:16384]
// chunk(ks,cg,kh,cl) = ((ks*2+cg)*2+kh)*32+cl; payload = 8 consecutive k,
// k = ks*16+kh*8+j, col = cg*32+cl.
__global__ void k_split_B(const float* __restrict__ rain, _Float16* __restrict__ Bimg) {
    int id = blockIdx.x * 256 + threadIdx.x;
    if (id >= CT2 * 1024) return;
    int cl = id & 31;
    int cg = (id >> 5) & 1;
    int kp = (id >> 6) & 15;           // ks = kp>>1, kh = kp&1
    int tc = id >> 10;
    int row = tc * 64 + cg * 32 + cl;
    const float4* src = (const float4*)(rain + (size_t)row * DD + kp * 8);
    float4 v0 = src[0], v1 = src[1];
    float x[8] = {v0.x, v0.y, v0.z, v0.w, v1.x, v1.y, v1.z, v1.w};
    _Float16 hi[8], lo[8];
    #pragma unroll
    for (int j = 0; j < 8; ++j) {
        _Float16 h = (_Float16)x[j];
        hi[j] = h;
        lo[j] = (_Float16)(x[j] - (float)h);
    }
    int ks = kp >> 1, kh = kp & 1;
    int chunk = ((ks * 2 + cg) * 2 + kh) * 32 + cl;
    size_t base = (size_t)tc * 16384;
    *(f16x8*)(Bimg + base + (size_t)chunk * 8) = *(f16x8*)hi;
    *(f16x8*)(Bimg + base + 8192 + (size_t)chunk * 8) = *(f16x8*)lo;
}

// W1 -> fp16 B-image for the MLP GEMM: chunk c = ((ks*4+cg)*2+kh)*32+cl;
// B[k][d] = W1[d][k], k = ks*16+kh*8+j, d = cg*32+cl. 4096 chunks = 64KB.
__global__ void k_w1img(const float* __restrict__ W1, _Float16* __restrict__ W1img) {
    int id = blockIdx.x * 256 + threadIdx.x;
    if (id >= 4096) return;
    int cl = id & 31;
    int kh = (id >> 5) & 1;
    int cg = (id >> 6) & 3;
    int ks = id >> 8;
    int d = cg * 32 + cl;
    int k = ks * 16 + kh * 8;
    const float4* src = (const float4*)(W1 + (size_t)d * 256 + k);
    float4 v0 = src[0], v1 = src[1];
    float x[8] = {v0.x, v0.y, v0.z, v0.w, v1.x, v1.y, v1.z, v1.w};
    _Float16 h[8];
    #pragma unroll
    for (int j = 0; j < 8; ++j) h[j] = (_Float16)x[j];
    *(f16x8*)(W1img + (size_t)id * 8) = *(f16x8*)h;
}

// MFMA distance GEMM + fused argmin. Block = 256 rows x 64-col tiles.
// Wave w: rows w*64..w*64+63 (2 row-blocks), both col-groups.
// Double-buffered 32KB tiles, ONE __syncthreads per iter.
// KEY (r8): y2 preloaded into registers -> the K-loop's ONLY vector-memory
// ops are the 8 prefetch DMAs, so nothing forces a vmcnt drain mid-compute.
__global__ __launch_bounds__(256, 2) void k_dist(
        const float* __restrict__ clear_f,
        const _Float16* __restrict__ Bimg, const float* __restrict__ y2,
        u64* __restrict__ keys2) {
    __shared__ _Float16 lds[2][16384];   // 2 x 32KB B-tile images

    const int tid = threadIdx.x;
    const int w = tid >> 6, lane = tid & 63;
    const int l5 = lane >> 5, l31 = lane & 31;
    const int b = blockIdx.x;
    const int split = b & 31;
    const int n0 = (b >> 5) * 256;
    const int nt = (CT2 - split + SPLITS - 1) / SPLITS;   // 7 or 8

    // Prologue prefetch: tile 0 -> buf 0 (32 segs of 1KB; 8 per wave)
    {
        const _Float16* gsrc = Bimg + (size_t)split * 16384;
        #pragma unroll
        for (int n = 0; n < 8; ++n) {
            int seg = w * 8 + n;
            __builtin_amdgcn_global_load_lds(
                (const __attribute__((address_space(1))) unsigned int*)
                    (gsrc + (size_t)seg * 512 + (size_t)lane * 8),
                (__attribute__((address_space(3))) unsigned int*)
                    (&lds[0][0] + (size_t)seg * 512),
                16, 0, 0);
        }
    }

    // A fragments: lane holds A[row=l31 of rb][k=ks*16+l5*8+j], split in-kernel
    f16x8 afh[2][8], afl[2][8];
    #pragma unroll
    for (int rb = 0; rb < 2; ++rb) {
        int r = n0 + w * 64 + rb * 32 + l31;
        if (r >= NN) r = NN - 1;
        const float* ap = clear_f + (size_t)r * DD + l5 * 8;
        #pragma unroll
        for (int ks = 0; ks < 8; ++ks) {
            float4 v0 = *(const float4*)(ap + ks * 16);
            float4 v1 = *(const float4*)(ap + ks * 16 + 4);
            float x[8] = {v0.x, v0.y, v0.z, v0.w, v1.x, v1.y, v1.z, v1.w};
            _Float16 hi[8], lo[8];
            #pragma unroll
            for (int j = 0; j < 8; ++j) {
                float s = -2.f * x[j];
                _Float16 h = (_Float16)s;
                hi[j] = h;
                lo[j] = (_Float16)(s - (float)h);
            }
            afh[rb][ks] = *(f16x8*)hi;
            afl[rb][ks] = *(f16x8*)lo;
        }
    }

    // Preload this split's y2 for ALL tiles into registers (<= 8 iters):
    // keeps the K-loop free of any global loads (no mid-loop vmcnt drains).
    float y2r0[8], y2r1[8];
    #pragma unroll
    for (int i = 0; i < 8; ++i) {
        int t = split + i * SPLITS;
        bool ok = i < nt;
        int tc = ok ? t : split;
        y2r0[i] = y2[tc * 64 + l31];
        y2r1[i] = y2[tc * 64 + 32 + l31];
    }

    __syncthreads();   // buf 0 ready

    float bestd[32];
    unsigned bits[4] = {0u, 0u, 0u, 0u};   // nibble/slot: (tile_idx<<1)|cg
    #pragma unroll
    for (int s = 0; s < 32; ++s) bestd[s] = 1e30f;

    int p = 0;
    for (int i = 0; i < nt; ++i) {
        const int t = split + i * SPLITS;

        // Prefetch next tile into the other buffer (overlaps compute on buf p)
        if (i + 1 < nt) {
            const _Float16* gsrc = Bimg + (size_t)(t + SPLITS) * 16384;
            _Float16* dst = &lds[1 - p][0];
            #pragma unroll
            for (int n = 0; n < 8; ++n) {
                int seg = w * 8 + n;
                __builtin_amdgcn_global_load_lds(
                    (const __attribute__((address_space(1))) unsigned int*)
                        (gsrc + (size_t)seg * 512 + (size_t)lane * 8),
                    (__attribute__((address_space(3))) unsigned int*)
                        (dst + (size_t)seg * 512),
                    16, 0, 0);
            }
        }

        float y2v0 = y2r0[i];
        float y2v1 = y2r1[i];

        // 4 independent accumulator chains (rb x cg); C-init carries y2
        f32x16 acc00, acc01, acc10, acc11;
        #pragma unroll
        for (int e = 0; e < 16; ++e) {
            acc00[e] = y2v0; acc10[e] = y2v0;
            acc01[e] = y2v1; acc11[e] = y2v1;
        }

        const _Float16* lbuf = &lds[p][0];
        #pragma unroll
        for (int ks = 0; ks < 8; ++ks) {
            f16x8 bh0 = *(const f16x8*)(lbuf + (size_t)(ks * 2 + 0) * 512 + (size_t)lane * 8);
            f16x8 bh1 = *(const f16x8*)(lbuf + (size_t)(ks * 2 + 1) * 512 + (size_t)lane * 8);
            f16x8 bl0 = *(const f16x8*)(lbuf + 8192 + (size_t)(ks * 2 + 0) * 512 + (size_t)lane * 8);
            f16x8 bl1 = *(const f16x8*)(lbuf + 8192 + (size_t)(ks * 2 + 1) * 512 + (size_t)lane * 8);
            // round-robin the 4 chains: waves of 4 independent MFMAs
            acc00 = __builtin_amdgcn_mfma_f32_32x32x16_f16(afh[0][ks], bh0, acc00, 0, 0, 0);
            acc10 = __builtin_amdgcn_mfma_f32_32x32x16_f16(afh[1][ks], bh0, acc10, 0, 0, 0);
            acc01 = __builtin_amdgcn_mfma_f32_32x32x16_f16(afh[0][ks], bh1, acc01, 0, 0, 0);
            acc11 = __builtin_amdgcn_mfma_f32_32x32x16_f16(afh[1][ks], bh1, acc11, 0, 0, 0);
            acc00 = __builtin_amdgcn_mfma_f32_32x32x16_f16(afh[0][ks], bl0, acc00, 0, 0, 0);
            acc10 = __builtin_amdgcn_mfma_f32_32x32x16_f16(afh[1][ks], bl0, acc10, 0, 0, 0);
            acc01 = __builtin_amdgcn_mfma_f32_32x32x16_f16(afh[0][ks], bl1, acc01, 0, 0, 0);
            acc11 = __builtin_amdgcn_mfma_f32_32x32x16_f16(afh[1][ks], bl1, acc11, 0, 0, 0);
            acc00 = __builtin_amdgcn_mfma_f32_32x32x16_f16(afl[0][ks], bh0, acc00, 0, 0, 0);
            acc10 = __builtin_amdgcn_mfma_f32_32x32x16_f16(afl[1][ks], bh0, acc10, 0, 0, 0);
            acc01 = __builtin_amdgcn_mfma_f32_32x32x16_f16(afl[0][ks], bh1, acc01, 0, 0, 0);
            acc11 = __builtin_amdgcn_mfma_f32_32x32x16_f16(afl[1][ks], bh1, acc11, 0, 0, 0);
        }

        // Fold: cg-pair min first (strict < prefers cg0 = lower col on tie),
        // then strict < vs running best (prefers earlier tile = lower col)
        const unsigned ibase = (unsigned)i << 1;
        #pragma unroll
        for (int e = 0; e < 16; ++e) {
            {
                float d0 = acc00[e], d1 = acc01[e];
                bool tk = d1 < d0;
                float dm = tk ? d1 : d0;
                int s = e, sh = 4 * (e & 7);
                bool up = dm < bestd[s];
                bestd[s] = up ? dm : bestd[s];
                unsigned nib = ibase | (unsigned)tk;
                bits[s >> 3] = up ? ((bits[s >> 3] & ~(15u << sh)) | (nib << sh))
                                  : bits[s >> 3];
            }
            {
                float d0 = acc10[e], d1 = acc11[e];
                bool tk = d1 < d0;
                float dm = tk ? d1 : d0;
                int s = 16 + e, sh = 4 * (s & 7);
                bool up = dm < bestd[s];
                bestd[s] = up ? dm : bestd[s];
                unsigned nib = ibase | (unsigned)tk;
                bits[s >> 3] = up ? ((bits[s >> 3] & ~(15u << sh)) | (nib << sh))
                                  : bits[s >> 3];
            }
        }

        __syncthreads();   // publishes prefetch (buf 1-p), frees buf p
        p ^= 1;
    }

    // Cross-lane min over the 32 l31 lanes, then one plain store per row.
    // Monotone sign-flip map (distances can be negative near the min).
    // C/D layout: col=lane&31, row=(e&3)+8*(e>>2)+4*l5
    #pragma unroll
    for (int s = 0; s < 32; ++s) {
        unsigned nib = (bits[s >> 3] >> (4 * (s & 7))) & 15u;
        int i4 = (int)(nib >> 1), cg = (int)(nib & 1);
        int col = (split + i4 * SPLITS) * 64 + cg * 32 + l31;
        unsigned u = __float_as_uint(bestd[s]);
        u = (u & 0x80000000u) ? ~u : (u | 0x80000000u);
        u64 key = ((u64)u << 32) | (unsigned)col;
        #pragma unroll
        for (int off = 1; off < 32; off <<= 1) {
            u64 o = __shfl_xor(key, off);
            if (o < key) key = o;
        }
        if (l31 == 0) {
            int e = s & 15, rb = s >> 4;
            int grow = n0 + w * 64 + rb * 32 + (e & 3) + 8 * (e >> 2) + 4 * l5;
            if (grow < NN) keys2[(size_t)grow * SPLITS + split] = key;
        }
    }
}

// Final argmin over the 32 split winners per row -> int index
__global__ void k_reduce(const u64* __restrict__ keys2, int* __restrict__ idx) {
    int n = blockIdx.x * 256 + threadIdx.x;
    if (n >= NN) return;
    const u64* p = keys2 + (size_t)n * SPLITS;
    u64 best = ~0ull;
    #pragma unroll
    for (int j = 0; j < SPLITS; ++j) {
        u64 k = p[j];
        if (k < best) best = k;
    }
    idx[n] = (int)(best & 0xffffffffu);
}

// MLP via fp16 MFMA: block = 128 rows (wave w: rows n0+w*32..+31).
// A-frag = comb row (clear|aligned) gathered+cvt straight into registers;
// B = W1 image staged once per block in LDS (64KB).
__global__ __launch_bounds__(256, 2) void k_mlp(
        const float* __restrict__ clear_f, const float* __restrict__ rain_f,
        const _Float16* __restrict__ W1img, const float* __restrict__ b1,
        const float* __restrict__ W2, const float* __restrict__ b2,
        const int* __restrict__ idx, float* __restrict__ out) {
    __shared__ _Float16 w1s[32768];   // 64KB

    const int tid = threadIdx.x;
    const int w = tid >> 6, lane = tid & 63;
    const int l5 = lane >> 5, l31 = lane & 31;
    const int n0 = blockIdx.x * 128;

    // Stage W1 image: 64 segs of 1KB
    #pragma unroll
    for (int n = 0; n < 16; ++n) {
        int seg = w * 16 + n;
        __builtin_amdgcn_global_load_lds(
            (const __attribute__((address_space(1))) unsigned int*)
                (W1img + (size_t)seg * 512 + (size_t)lane * 8),
            (__attribute__((address_space(3))) unsigned int*)
                (&w1s[0] + (size_t)seg * 512),
            16, 0, 0);
    }

    // Gather A-fragments: row = l31's comb row; k<128 clear, k>=128 aligned
    int n = n0 + w * 32 + l31;
    int nc = n < NN ? n : NN - 1;
    int rid = idx[nc];
    f16x8 af[16];
    #pragma unroll
    for (int ks = 0; ks < 16; ++ks) {
        int k0 = ks * 16 + l5 * 8;
        const float4* src = (k0 < 128)
            ? (const float4*)(clear_f + (size_t)nc * DD + k0)
            : (const float4*)(rain_f + (size_t)rid * DD + (k0 - 128));
        float4 v0 = src[0], v1 = src[1];
        float x[8] = {v0.x, v0.y, v0.z, v0.w, v1.x, v1.y, v1.z, v1.w};
        _Float16 h[8];
        #pragma unroll
        for (int j = 0; j < 8; ++j) h[j] = (_Float16)x[j];
        af[ks] = *(f16x8*)h;
    }

    __syncthreads();   // w1s ready

    f32x16 acc[4];
    #pragma unroll
    for (int cg = 0; cg < 4; ++cg)
        #pragma unroll
        for (int e = 0; e < 16; ++e) acc[cg][e] = 0.f;

    #pragma unroll
    for (int ks = 0; ks < 16; ++ks) {
        #pragma unroll
        for (int cg = 0; cg < 4; ++cg) {
            f16x8 bh = *(const f16x8*)(&w1s[0] +
                ((size_t)((ks * 4 + cg) * 2 + l5)) * 256 + (size_t)l31 * 8);
            acc[cg] = __builtin_amdgcn_mfma_f32_32x32x16_f16(af[ks], bh, acc[cg], 0, 0, 0);
        }
    }

    // Epilogue: lane holds h[row(e,l5)][d = cg*32 + l31]
    float b1v[4], w2v[4];
    #pragma unroll
    for (int cg = 0; cg < 4; ++cg) {
        b1v[cg] = b1[cg * 32 + l31];
        w2v[cg] = W2[cg * 32 + l31];
    }
    float b2v = b2[0];

    #pragma unroll
    for (int e = 0; e < 16; ++e) {
        float part = 0.f;
        #pragma unroll
        for (int cg = 0; cg < 4; ++cg) {
            float hv = acc[cg][e] + b1v[cg];
            hv = hv > 0.f ? hv : 0.f;
            part = fmaf(hv, w2v[cg], part);
        }
        #pragma unroll
        for (int off = 1; off < 32; off <<= 1) part += __shfl_xor(part, off);
        float s = part + b2v;
        float wv = 1.f / (1.f + expf(-s));
        int row = n0 + w * 32 + (e & 3) + 8 * (e >> 2) + 4 * l5;
        if (row < NN) {
            int rid2 = idx[row];
            float4 cv = *(const float4*)(clear_f + (size_t)row * DD + l31 * 4);
            float4 av = *(const float4*)(rain_f + (size_t)rid2 * DD + l31 * 4);
            float4 ov;
            ov.x = wv * cv.x + (1.f - wv) * av.x;
            ov.y = wv * cv.y + (1.f - wv) * av.y;
            ov.z = wv * cv.z + (1.f - wv) * av.z;
            ov.w = wv * cv.w + (1.f - wv) * av.w;
            *(float4*)(out + (size_t)row * DD + l31 * 4) = ov;
        }
    }
}

extern "C" void kernel_launch(void* const* d_in, const int* in_sizes, int n_in,
                              void* d_out, int out_size, void* d_ws, size_t ws_size,
                              hipStream_t stream) {
    const float* clear_f = (const float*)d_in[0];
    const float* rain_f = (const float*)d_in[1];
    const float* W1 = (const float*)d_in[2];
    const float* b1 = (const float*)d_in[3];
    const float* W2 = (const float*)d_in[4];
    const float* b2 = (const float*)d_in[5];
    float* out = (float*)d_out;

    char* ws = (char*)d_ws;
    u64* keys2 = (u64*)ws;                                 // 5,120,000 B
    int* idx = (int*)(ws + 5120000);                       // 80,000 B
    float* y2 = (float*)(ws + 5200000);                    // 64,000 B
    _Float16* Bimg = (_Float16*)(ws + 5264000);            // 8,192,000 B
    _Float16* W1img = (_Float16*)(ws + 13456000);          // 65,536 B  (end 13.52MB)

    k_y2<<<MM / 4, 256, 0, stream>>>(rain_f, y2);
    k_split_B<<<(CT2 * 1024 + 255) / 256, 256, 0, stream>>>(rain_f, Bimg);
    k_w1img<<<16, 256, 0, stream>>>(W1, W1img);
    k_dist<<<RB * SPLITS, 256, 0, stream>>>(clear_f, Bimg, y2, keys2);
    k_reduce<<<(NN + 255) / 256, 256, 0, stream>>>(keys2, idx);
    k_mlp<<<(NN + 127) / 128, 256, 0, stream>>>(clear_f, rain_f, W1img, b1, W2, b2, idx, out);
}

// Round 9
// 355.293 us; speedup vs baseline: 1.1994x; 1.1994x over previous
//
#include <hip/hip_runtime.h>
#include <stdint.h>

#define NN 20000
#define MM 16000
#define DD 128
#define CT2 250       // 16000 / 64 col-tiles
#define SPLITS 32     // multiple of 8 -> split % 8 == XCD id (L2 locality)
#define RB 79         // ceil(20000/256) row blocks

typedef unsigned long long u64;
typedef _Float16 f16x8 __attribute__((ext_vector_type(8)));
typedef float f32x16 __attribute__((ext_vector_type(16)));

// One wave per rain row: y2[m] = ||rain[m]||^2 (fp32, unbiased — r5/r6
// post-mortem: +512 bias coarsened accumulator ulp 8x and flipped argmins)
__global__ void k_y2(const float* __restrict__ rain, float* __restrict__ y2) {
    int row = blockIdx.x * 4 + (threadIdx.x >> 6);
    int lane = threadIdx.x & 63;
    if (row >= MM) return;
    float2 v = ((const float2*)(rain + (size_t)row * DD))[lane];
    float s = v.x * v.x + v.y * v.y;
    #pragma unroll
    for (int off = 32; off > 0; off >>= 1) s += __shfl_down(s, off);
    if (lane == 0) y2[row] = s;
}

// Split rain into fp16 hi/lo 64-col tile images (32KB per tile):
// tile tc: hi f16[0:8192], lo f16[8192:16384]
// chunk(ks,cg,kh,cl) = ((ks*2+cg)*2+kh)*32+cl; payload = 8 consecutive k,
// k = ks*16+kh*8+j, col = cg*32+cl.
__global__ void k_split_B(const float* __restrict__ rain, _Float16* __restrict__ Bimg) {
    int id = blockIdx.x * 256 + threadIdx.x;
    if (id >= CT2 * 1024) return;
    int cl = id & 31;
    int cg = (id >> 5) & 1;
    int kp = (id >> 6) & 15;           // ks = kp>>1, kh = kp&1
    int tc = id >> 10;
    int row = tc * 64 + cg * 32 + cl;
    const float4* src = (const float4*)(rain + (size_t)row * DD + kp * 8);
    float4 v0 = src[0], v1 = src[1];
    float x[8] = {v0.x, v0.y, v0.z, v0.w, v1.x, v1.y, v1.z, v1.w};
    _Float16 hi[8], lo[8];
    #pragma unroll
    for (int j = 0; j < 8; ++j) {
        _Float16 h = (_Float16)x[j];
        hi[j] = h;
        lo[j] = (_Float16)(x[j] - (float)h);
    }
    int ks = kp >> 1, kh = kp & 1;
    int chunk = ((ks * 2 + cg) * 2 + kh) * 32 + cl;
    size_t base = (size_t)tc * 16384;
    *(f16x8*)(Bimg + base + (size_t)chunk * 8) = *(f16x8*)hi;
    *(f16x8*)(Bimg + base + 8192 + (size_t)chunk * 8) = *(f16x8*)lo;
}

// W1 -> fp16 B-image for the MLP GEMM: chunk c = ((ks*4+cg)*2+kh)*32+cl;
// B[k][d] = W1[d][k], k = ks*16+kh*8+j, d = cg*32+cl. 4096 chunks = 64KB.
__global__ void k_w1img(const float* __restrict__ W1, _Float16* __restrict__ W1img) {
    int id = blockIdx.x * 256 + threadIdx.x;
    if (id >= 4096) return;
    int cl = id & 31;
    int kh = (id >> 5) & 1;
    int cg = (id >> 6) & 3;
    int ks = id >> 8;
    int d = cg * 32 + cl;
    int k = ks * 16 + kh * 8;
    const float4* src = (const float4*)(W1 + (size_t)d * 256 + k);
    float4 v0 = src[0], v1 = src[1];
    float x[8] = {v0.x, v0.y, v0.z, v0.w, v1.x, v1.y, v1.z, v1.w};
    _Float16 h[8];
    #pragma unroll
    for (int j = 0; j < 8; ++j) h[j] = (_Float16)x[j];
    *(f16x8*)(W1img + (size_t)id * 8) = *(f16x8*)h;
}

// MFMA distance GEMM + fused argmin. Block = 256 rows x 64-col tiles.
// Wave w: rows w*64..w*64+63 (2 row-blocks), both col-groups.
// Double-buffered 32KB tiles, ONE __syncthreads per iter.
// y2 staged in an LDS SIDECAR (ds_read in-loop: lgkmcnt domain, no vmcnt
// interaction, no register-array dynamic indexing -> no scratch spill).
__global__ __launch_bounds__(256, 2) void k_dist(
        const float* __restrict__ clear_f,
        const _Float16* __restrict__ Bimg, const float* __restrict__ y2,
        u64* __restrict__ keys2) {
    __shared__ _Float16 lds[2][16384];   // 2 x 32KB B-tile images
    __shared__ float y2s[512];           // [tile][col-in-tile], nt*64 <= 512

    const int tid = threadIdx.x;
    const int w = tid >> 6, lane = tid & 63;
    const int l5 = lane >> 5, l31 = lane & 31;
    const int b = blockIdx.x;
    const int split = b & 31;
    const int n0 = (b >> 5) * 256;
    const int nt = (CT2 - split + SPLITS - 1) / SPLITS;   // 7 or 8

    // Prologue prefetch: tile 0 -> buf 0 (32 segs of 1KB; 8 per wave)
    {
        const _Float16* gsrc = Bimg + (size_t)split * 16384;
        #pragma unroll
        for (int n = 0; n < 8; ++n) {
            int seg = w * 8 + n;
            __builtin_amdgcn_global_load_lds(
                (const __attribute__((address_space(1))) unsigned int*)
                    (gsrc + (size_t)seg * 512 + (size_t)lane * 8),
                (__attribute__((address_space(3))) unsigned int*)
                    (&lds[0][0] + (size_t)seg * 512),
                16, 0, 0);
        }
    }

    // Stage this split's y2 into the LDS sidecar
    for (int j = tid; j < nt * 64; j += 256) {
        int tt = j >> 6;
        int cc = j & 63;
        y2s[j] = y2[(split + tt * SPLITS) * 64 + cc];
    }

    // A fragments: lane holds A[row=l31 of rb][k=ks*16+l5*8+j], split in-kernel
    f16x8 afh[2][8], afl[2][8];
    #pragma unroll
    for (int rb = 0; rb < 2; ++rb) {
        int r = n0 + w * 64 + rb * 32 + l31;
        if (r >= NN) r = NN - 1;
        const float* ap = clear_f + (size_t)r * DD + l5 * 8;
        #pragma unroll
        for (int ks = 0; ks < 8; ++ks) {
            float4 v0 = *(const float4*)(ap + ks * 16);
            float4 v1 = *(const float4*)(ap + ks * 16 + 4);
            float x[8] = {v0.x, v0.y, v0.z, v0.w, v1.x, v1.y, v1.z, v1.w};
            _Float16 hi[8], lo[8];
            #pragma unroll
            for (int j = 0; j < 8; ++j) {
                float s = -2.f * x[j];
                _Float16 h = (_Float16)s;
                hi[j] = h;
                lo[j] = (_Float16)(s - (float)h);
            }
            afh[rb][ks] = *(f16x8*)hi;
            afl[rb][ks] = *(f16x8*)lo;
        }
    }

    __syncthreads();   // buf 0 + y2s ready

    float bestd[32];
    unsigned bits[4] = {0u, 0u, 0u, 0u};   // nibble/slot: (tile_idx<<1)|cg
    #pragma unroll
    for (int s = 0; s < 32; ++s) bestd[s] = 1e30f;

    int p = 0;
    for (int i = 0; i < nt; ++i) {
        const int t = split + i * SPLITS;

        // Prefetch next tile into the other buffer (overlaps compute on buf p)
        if (i + 1 < nt) {
            const _Float16* gsrc = Bimg + (size_t)(t + SPLITS) * 16384;
            _Float16* dst = &lds[1 - p][0];
            #pragma unroll
            for (int n = 0; n < 8; ++n) {
                int seg = w * 8 + n;
                __builtin_amdgcn_global_load_lds(
                    (const __attribute__((address_space(1))) unsigned int*)
                        (gsrc + (size_t)seg * 512 + (size_t)lane * 8),
                    (__attribute__((address_space(3))) unsigned int*)
                        (dst + (size_t)seg * 512),
                    16, 0, 0);
            }
        }

        float y2v0 = y2s[i * 64 + l31];          // ds_read_b32, lgkmcnt only
        float y2v1 = y2s[i * 64 + 32 + l31];

        // 4 independent accumulator chains (rb x cg); C-init carries y2
        f32x16 acc00, acc01, acc10, acc11;
        #pragma unroll
        for (int e = 0; e < 16; ++e) {
            acc00[e] = y2v0; acc10[e] = y2v0;
            acc01[e] = y2v1; acc11[e] = y2v1;
        }

        const _Float16* lbuf = &lds[p][0];
        #pragma unroll
        for (int ks = 0; ks < 8; ++ks) {
            f16x8 bh0 = *(const f16x8*)(lbuf + (size_t)(ks * 2 + 0) * 512 + (size_t)lane * 8);
            f16x8 bh1 = *(const f16x8*)(lbuf + (size_t)(ks * 2 + 1) * 512 + (size_t)lane * 8);
            f16x8 bl0 = *(const f16x8*)(lbuf + 8192 + (size_t)(ks * 2 + 0) * 512 + (size_t)lane * 8);
            f16x8 bl1 = *(const f16x8*)(lbuf + 8192 + (size_t)(ks * 2 + 1) * 512 + (size_t)lane * 8);
            // round-robin the 4 chains: waves of 4 independent MFMAs
            acc00 = __builtin_amdgcn_mfma_f32_32x32x16_f16(afh[0][ks], bh0, acc00, 0, 0, 0);
            acc10 = __builtin_amdgcn_mfma_f32_32x32x16_f16(afh[1][ks], bh0, acc10, 0, 0, 0);
            acc01 = __builtin_amdgcn_mfma_f32_32x32x16_f16(afh[0][ks], bh1, acc01, 0, 0, 0);
            acc11 = __builtin_amdgcn_mfma_f32_32x32x16_f16(afh[1][ks], bh1, acc11, 0, 0, 0);
            acc00 = __builtin_amdgcn_mfma_f32_32x32x16_f16(afh[0][ks], bl0, acc00, 0, 0, 0);
            acc10 = __builtin_amdgcn_mfma_f32_32x32x16_f16(afh[1][ks], bl0, acc10, 0, 0, 0);
            acc01 = __builtin_amdgcn_mfma_f32_32x32x16_f16(afh[0][ks], bl1, acc01, 0, 0, 0);
            acc11 = __builtin_amdgcn_mfma_f32_32x32x16_f16(afh[1][ks], bl1, acc11, 0, 0, 0);
            acc00 = __builtin_amdgcn_mfma_f32_32x32x16_f16(afl[0][ks], bh0, acc00, 0, 0, 0);
            acc10 = __builtin_amdgcn_mfma_f32_32x32x16_f16(afl[1][ks], bh0, acc10, 0, 0, 0);
            acc01 = __builtin_amdgcn_mfma_f32_32x32x16_f16(afl[0][ks], bh1, acc01, 0, 0, 0);
            acc11 = __builtin_amdgcn_mfma_f32_32x32x16_f16(afl[1][ks], bh1, acc11, 0, 0, 0);
        }

        // Fold: cg-pair min first (strict < prefers cg0 = lower col on tie),
        // then strict < vs running best (prefers earlier tile = lower col)
        const unsigned ibase = (unsigned)i << 1;
        #pragma unroll
        for (int e = 0; e < 16; ++e) {
            {
                float d0 = acc00[e], d1 = acc01[e];
                bool tk = d1 < d0;
                float dm = tk ? d1 : d0;
                int s = e, sh = 4 * (e & 7);
                bool up = dm < bestd[s];
                bestd[s] = up ? dm : bestd[s];
                unsigned nib = ibase | (unsigned)tk;
                bits[s >> 3] = up ? ((bits[s >> 3] & ~(15u << sh)) | (nib << sh))
                                  : bits[s >> 3];
            }
            {
                float d0 = acc10[e], d1 = acc11[e];
                bool tk = d1 < d0;
                float dm = tk ? d1 : d0;
                int s = 16 + e, sh = 4 * (s & 7);
                bool up = dm < bestd[s];
                bestd[s] = up ? dm : bestd[s];
                unsigned nib = ibase | (unsigned)tk;
                bits[s >> 3] = up ? ((bits[s >> 3] & ~(15u << sh)) | (nib << sh))
                                  : bits[s >> 3];
            }
        }

        __syncthreads();   // publishes prefetch (buf 1-p), frees buf p
        p ^= 1;
    }

    // Cross-lane min over the 32 l31 lanes, then one plain store per row.
    // Monotone sign-flip map (distances can be negative near the min).
    // C/D layout: col=lane&31, row=(e&3)+8*(e>>2)+4*l5
    #pragma unroll
    for (int s = 0; s < 32; ++s) {
        unsigned nib = (bits[s >> 3] >> (4 * (s & 7))) & 15u;
        int i4 = (int)(nib >> 1), cg = (int)(nib & 1);
        int col = (split + i4 * SPLITS) * 64 + cg * 32 + l31;
        unsigned u = __float_as_uint(bestd[s]);
        u = (u & 0x80000000u) ? ~u : (u | 0x80000000u);
        u64 key = ((u64)u << 32) | (unsigned)col;
        #pragma unroll
        for (int off = 1; off < 32; off <<= 1) {
            u64 o = __shfl_xor(key, off);
            if (o < key) key = o;
        }
        if (l31 == 0) {
            int e = s & 15, rb = s >> 4;
            int grow = n0 + w * 64 + rb * 32 + (e & 3) + 8 * (e >> 2) + 4 * l5;
            if (grow < NN) keys2[(size_t)grow * SPLITS + split] = key;
        }
    }
}

// Final argmin over the 32 split winners per row -> int index
__global__ void k_reduce(const u64* __restrict__ keys2, int* __restrict__ idx) {
    int n = blockIdx.x * 256 + threadIdx.x;
    if (n >= NN) return;
    const u64* p = keys2 + (size_t)n * SPLITS;
    u64 best = ~0ull;
    #pragma unroll
    for (int j = 0; j < SPLITS; ++j) {
        u64 k = p[j];
        if (k < best) best = k;
    }
    idx[n] = (int)(best & 0xffffffffu);
}

// MLP via fp16 MFMA: block = 128 rows (wave w: rows n0+w*32..+31).
// A-frag = comb row (clear|aligned) gathered+cvt straight into registers;
// B = W1 image staged once per block in LDS (64KB).
__global__ __launch_bounds__(256, 2) void k_mlp(
        const float* __restrict__ clear_f, const float* __restrict__ rain_f,
        const _Float16* __restrict__ W1img, const float* __restrict__ b1,
        const float* __restrict__ W2, const float* __restrict__ b2,
        const int* __restrict__ idx, float* __restrict__ out) {
    __shared__ _Float16 w1s[32768];   // 64KB

    const int tid = threadIdx.x;
    const int w = tid >> 6, lane = tid & 63;
    const int l5 = lane >> 5, l31 = lane & 31;
    const int n0 = blockIdx.x * 128;

    // Stage W1 image: 64 segs of 1KB
    #pragma unroll
    for (int n = 0; n < 16; ++n) {
        int seg = w * 16 + n;
        __builtin_amdgcn_global_load_lds(
            (const __attribute__((address_space(1))) unsigned int*)
                (W1img + (size_t)seg * 512 + (size_t)lane * 8),
            (__attribute__((address_space(3))) unsigned int*)
                (&w1s[0] + (size_t)seg * 512),
            16, 0, 0);
    }

    // Gather A-fragments: row = l31's comb row; k<128 clear, k>=128 aligned
    int n = n0 + w * 32 + l31;
    int nc = n < NN ? n : NN - 1;
    int rid = idx[nc];
    f16x8 af[16];
    #pragma unroll
    for (int ks = 0; ks < 16; ++ks) {
        int k0 = ks * 16 + l5 * 8;
        const float4* src = (k0 < 128)
            ? (const float4*)(clear_f + (size_t)nc * DD + k0)
            : (const float4*)(rain_f + (size_t)rid * DD + (k0 - 128));
        float4 v0 = src[0], v1 = src[1];
        float x[8] = {v0.x, v0.y, v0.z, v0.w, v1.x, v1.y, v1.z, v1.w};
        _Float16 h[8];
        #pragma unroll
        for (int j = 0; j < 8; ++j) h[j] = (_Float16)x[j];
        af[ks] = *(f16x8*)h;
    }

    __syncthreads();   // w1s ready

    f32x16 acc[4];
    #pragma unroll
    for (int cg = 0; cg < 4; ++cg)
        #pragma unroll
        for (int e = 0; e < 16; ++e) acc[cg][e] = 0.f;

    #pragma unroll
    for (int ks = 0; ks < 16; ++ks) {
        #pragma unroll
        for (int cg = 0; cg < 4; ++cg) {
            f16x8 bh = *(const f16x8*)(&w1s[0] +
                ((size_t)((ks * 4 + cg) * 2 + l5)) * 256 + (size_t)l31 * 8);
            acc[cg] = __builtin_amdgcn_mfma_f32_32x32x16_f16(af[ks], bh, acc[cg], 0, 0, 0);
        }
    }

    // Epilogue: lane holds h[row(e,l5)][d = cg*32 + l31]
    float b1v[4], w2v[4];
    #pragma unroll
    for (int cg = 0; cg < 4; ++cg) {
        b1v[cg] = b1[cg * 32 + l31];
        w2v[cg] = W2[cg * 32 + l31];
    }
    float b2v = b2[0];

    #pragma unroll
    for (int e = 0; e < 16; ++e) {
        float part = 0.f;
        #pragma unroll
        for (int cg = 0; cg < 4; ++cg) {
            float hv = acc[cg][e] + b1v[cg];
            hv = hv > 0.f ? hv : 0.f;
            part = fmaf(hv, w2v[cg], part);
        }
        #pragma unroll
        for (int off = 1; off < 32; off <<= 1) part += __shfl_xor(part, off);
        float s = part + b2v;
        float wv = 1.f / (1.f + expf(-s));
        int row = n0 + w * 32 + (e & 3) + 8 * (e >> 2) + 4 * l5;
        if (row < NN) {
            int rid2 = idx[row];
            float4 cv = *(const float4*)(clear_f + (size_t)row * DD + l31 * 4);
            float4 av = *(const float4*)(rain_f + (size_t)rid2 * DD + l31 * 4);
            float4 ov;
            ov.x = wv * cv.x + (1.f - wv) * av.x;
            ov.y = wv * cv.y + (1.f - wv) * av.y;
            ov.z = wv * cv.z + (1.f - wv) * av.z;
            ov.w = wv * cv.w + (1.f - wv) * av.w;
            *(float4*)(out + (size_t)row * DD + l31 * 4) = ov;
        }
    }
}

extern "C" void kernel_launch(void* const* d_in, const int* in_sizes, int n_in,
                              void* d_out, int out_size, void* d_ws, size_t ws_size,
                              hipStream_t stream) {
    const float* clear_f = (const float*)d_in[0];
    const float* rain_f = (const float*)d_in[1];
    const float* W1 = (const float*)d_in[2];
    const float* b1 = (const float*)d_in[3];
    const float* W2 = (const float*)d_in[4];
    const float* b2 = (const float*)d_in[5];
    float* out = (float*)d_out;

    char* ws = (char*)d_ws;
    u64* keys2 = (u64*)ws;                                 // 5,120,000 B
    int* idx = (int*)(ws + 5120000);                       // 80,000 B
    float* y2 = (float*)(ws + 5200000);                    // 64,000 B
    _Float16* Bimg = (_Float16*)(ws + 5264000);            // 8,192,000 B
    _Float16* W1img = (_Float16*)(ws + 13456000);          // 65,536 B  (end 13.52MB)

    k_y2<<<MM / 4, 256, 0, stream>>>(rain_f, y2);
    k_split_B<<<(CT2 * 1024 + 255) / 256, 256, 0, stream>>>(rain_f, Bimg);
    k_w1img<<<16, 256, 0, stream>>>(W1, W1img);
    k_dist<<<RB * SPLITS, 256, 0, stream>>>(clear_f, Bimg, y2, keys2);
    k_reduce<<<(NN + 255) / 256, 256, 0, stream>>>(keys2, idx);
    k_mlp<<<(NN + 127) / 128, 256, 0, stream>>>(clear_f, rain_f, W1img, b1, W2, b2, idx, out);
}